// Round 2
// baseline (483.277 us; speedup 1.0000x reference)
//
#include <hip/hip_runtime.h>
#include <hip/hip_bf16.h>

// GCN layer, 3-pass:
//   gcn_prep : read adj fp32 (256MB) -> adjb bf16 (128MB, ws) + rowsum -> dinv
//   gcn_build: yT[f][j] = bf16(dinv_j * x[j][f]) (2MB), Wb = bf16(W)
//   gcn_main : h0 = adjb @ y via MFMA, A streamed with global_load_lds_dwordx4
//              (XOR-swizzled 16B blocks to kill LDS bank conflicts), fused
//              epilogue: t = dinv_i*h0 + dinv_i^2*x ; z = t@W^T + b ; L2-norm.
//
// ws: [0,128MB) adjb | [128MB,+2MB) yT | +32KB dinv | +32KB Wb

typedef __attribute__((ext_vector_type(8))) short short8;     // 8 x bf16
typedef __attribute__((ext_vector_type(4))) float f32x4;      // MFMA acc
typedef __attribute__((ext_vector_type(4))) unsigned short us4;

static __device__ __forceinline__ unsigned short f2bf(float f) {
    unsigned int u = __float_as_uint(f);
    u += 0x7FFFu + ((u >> 16) & 1u);        // RNE
    return (unsigned short)(u >> 16);
}

static __device__ __forceinline__ void gload_lds16(const void* g, void* l) {
    __builtin_amdgcn_global_load_lds(
        (const __attribute__((address_space(1))) unsigned int*)g,
        (__attribute__((address_space(3))) unsigned int*)l, 16, 0, 0);
}

// ---------------------------------------------------------------- pass 1 ----
__global__ __launch_bounds__(256) void gcn_prep(
    const float* __restrict__ adj, unsigned short* __restrict__ adjb,
    float* __restrict__ dinv)
{
    const int tid = threadIdx.x;
    const long j = blockIdx.x;
    const float4* row = (const float4*)(adj + j * 8192L);
    us4* brow = (us4*)(adjb + j * 8192L);
    float s = 0.f;
#pragma unroll
    for (int it = 0; it < 8; ++it) {        // 256 thr * 8 * 4 = 8192 floats
        float4 v = row[it * 256 + tid];
        s += v.x + v.y + v.z + v.w;
        us4 w;
        w.x = f2bf(v.x); w.y = f2bf(v.y); w.z = f2bf(v.z); w.w = f2bf(v.w);
        brow[it * 256 + tid] = w;
    }
    for (int off = 1; off < 64; off <<= 1) s += __shfl_xor(s, off, 64);
    __shared__ float ps[4];
    if ((tid & 63) == 0) ps[tid >> 6] = s;
    __syncthreads();
    if (tid == 0)
        dinv[j] = rsqrtf(ps[0] + ps[1] + ps[2] + ps[3] + 1.0f);  // +1 self loop
}

// ---------------------------------------------------------------- pass 2 ----
__global__ __launch_bounds__(256) void gcn_build(
    const float* __restrict__ x, const float* __restrict__ W,
    const float* __restrict__ dinv,
    unsigned short* __restrict__ yT, unsigned short* __restrict__ Wb)
{
    __shared__ float xs[64][129];
    __shared__ float sd[64];
    const int tid = threadIdx.x;
    const long j0 = (long)blockIdx.x * 64;
    if (blockIdx.x == 0)
        for (int i = tid; i < 16384; i += 256) Wb[i] = f2bf(W[i]);
    if (tid < 64) sd[tid] = dinv[j0 + tid];
    const float4* xg = (const float4*)(x + j0 * 128);
#pragma unroll
    for (int it = 0; it < 8; ++it) {        // 64 rows x 32 float4
        int idx = it * 256 + tid;
        int r = idx >> 5, c4 = idx & 31;
        float4 v = xg[idx];
        xs[r][c4 * 4 + 0] = v.x; xs[r][c4 * 4 + 1] = v.y;
        xs[r][c4 * 4 + 2] = v.z; xs[r][c4 * 4 + 3] = v.w;
    }
    __syncthreads();
    const int jj = tid & 63, fg = tid >> 6;
    const float d = sd[jj];
#pragma unroll
    for (int f = fg; f < 128; f += 4)
        yT[(long)f * 8192 + j0 + jj] = f2bf(d * xs[jj][f]);
}

// ---------------------------------------------------------------- pass 3 ----
#define M_TILE 32
#define BKC    512
#define NCHUNK 16

__global__ __launch_bounds__(256, 1) void gcn_main(
    const unsigned short* __restrict__ adjb, const float* __restrict__ x,
    const float* __restrict__ bias,
    const unsigned short* __restrict__ yT, const float* __restrict__ dinv,
    const unsigned short* __restrict__ Wb, float* __restrict__ out)
{
    __shared__ unsigned short Ab[2][M_TILE][BKC];   // 64 KB

    const int tid  = threadIdx.x;
    const int wave = tid >> 6;
    const int lane = tid & 63;
    const int q    = lane >> 4;
    const int ln   = lane & 15;
    const int nb   = wave * 32;
    const long rowBase = (long)blockIdx.x * M_TILE;

    f32x4 acc[2][2] = {};

    // async fill: one dwordx4 per lane per row; 16B blocks XOR-swizzled by
    // (row&7) so the strided fragment reads below are 2-way (free) not 16-way.
    auto issue = [&](int c, int buf) {
#pragma unroll
        for (int i = 0; i < 8; ++i) {
            int r = wave * 8 + i;
            const unsigned short* g =
                adjb + (rowBase + r) * 8192L + (long)c * BKC + ((lane ^ (r & 7)) << 3);
            gload_lds16(g, &Ab[buf][r][0]);   // lane l -> base + l*16
        }
    };

    issue(0, 0);

    const unsigned short* bp0 = yT + (long)(nb + ln) * 8192;
    const unsigned short* bp1 = bp0 + 16 * 8192L;
    const int swz = ln & 7;                  // (16+ln)&7 == ln&7: same for a1

#pragma unroll 1
    for (int c = 0; c < NCHUNK; ++c) {
        const int cur = c & 1;
        __syncthreads();                     // drains this chunk's DMA
        if (c + 1 < NCHUNK) issue(c + 1, cur ^ 1);   // flies during compute
#pragma unroll 4
        for (int s = 0; s < BKC / 32; ++s) {
            const int cb = (((s * 4 + q) ^ swz) << 3);
            short8 a0 = *(const short8*)&Ab[cur][ln][cb];
            short8 a1 = *(const short8*)&Ab[cur][16 + ln][cb];
            const long kg = (long)c * BKC + s * 32 + q * 8;
            short8 b0 = *(const short8*)&bp0[kg];
            short8 b1 = *(const short8*)&bp1[kg];
            acc[0][0] = __builtin_amdgcn_mfma_f32_16x16x32_bf16(a0, b0, acc[0][0], 0, 0, 0);
            acc[0][1] = __builtin_amdgcn_mfma_f32_16x16x32_bf16(a0, b1, acc[0][1], 0, 0, 0);
            acc[1][0] = __builtin_amdgcn_mfma_f32_16x16x32_bf16(a1, b0, acc[1][0], 0, 0, 0);
            acc[1][1] = __builtin_amdgcn_mfma_f32_16x16x32_bf16(a1, b1, acc[1][1], 0, 0, 0);
        }
    }

    // ---- fused epilogue (scratch overlays Ab[0]; last compute read Ab[1]) ----
    unsigned short* t_lds = &Ab[0][0][0];           // [32][136] bf16
    float* s_dinv = (float*)(t_lds + 32 * 136);
    float* s_part = s_dinv + 32;                    // [32][4]
    float* s_inv  = s_part + 128;                   // [32]

    if (tid < 32) s_dinv[tid] = dinv[rowBase + tid];
    __syncthreads();

    // t = dinv_i * (adj@y)_i + dinv_i^2 * x_i  -> LDS bf16
#pragma unroll
    for (int mi = 0; mi < 2; ++mi)
#pragma unroll
        for (int nj = 0; nj < 2; ++nj)
#pragma unroll
            for (int r = 0; r < 4; ++r) {
                int m = mi * 16 + q * 4 + r;
                int n = nb + nj * 16 + ln;
                float di = s_dinv[m];
                float tv = di * acc[mi][nj][r] + di * di * x[(rowBase + m) * 128 + n];
                t_lds[m * 136 + n] = f2bf(tv);
            }
    __syncthreads();

    // z = t @ W^T via MFMA
    f32x4 z[2][2] = {};
#pragma unroll
    for (int s = 0; s < 4; ++s) {
        const int k0 = s * 32 + q * 8;
        short8 a0 = *(const short8*)&t_lds[ln * 136 + k0];
        short8 a1 = *(const short8*)&t_lds[(16 + ln) * 136 + k0];
        short8 b0 = *(const short8*)&Wb[(nb + ln) * 128 + k0];
        short8 b1 = *(const short8*)&Wb[(nb + 16 + ln) * 128 + k0];
        z[0][0] = __builtin_amdgcn_mfma_f32_16x16x32_bf16(a0, b0, z[0][0], 0, 0, 0);
        z[0][1] = __builtin_amdgcn_mfma_f32_16x16x32_bf16(a0, b1, z[0][1], 0, 0, 0);
        z[1][0] = __builtin_amdgcn_mfma_f32_16x16x32_bf16(a1, b0, z[1][0], 0, 0, 0);
        z[1][1] = __builtin_amdgcn_mfma_f32_16x16x32_bf16(a1, b1, z[1][1], 0, 0, 0);
    }

    float bv0 = bias[nb + ln], bv1 = bias[nb + 16 + ln];
    float zv[2][2][4];
    float rp[2][4];
#pragma unroll
    for (int mi = 0; mi < 2; ++mi)
#pragma unroll
        for (int r = 0; r < 4; ++r) {
            float v0 = z[mi][0][r] + bv0;
            float v1 = z[mi][1][r] + bv1;
            zv[mi][0][r] = v0; zv[mi][1][r] = v1;
            rp[mi][r] = v0 * v0 + v1 * v1;
        }
#pragma unroll
    for (int mi = 0; mi < 2; ++mi)
#pragma unroll
        for (int r = 0; r < 4; ++r)
            for (int off = 1; off < 16; off <<= 1)
                rp[mi][r] += __shfl_xor(rp[mi][r], off, 64);
    if (ln == 0) {
#pragma unroll
        for (int mi = 0; mi < 2; ++mi)
#pragma unroll
            for (int r = 0; r < 4; ++r)
                s_part[(mi * 16 + q * 4 + r) * 4 + wave] = rp[mi][r];
    }
    __syncthreads();
    if (tid < 32) {
        float ssum = s_part[tid * 4] + s_part[tid * 4 + 1] + s_part[tid * 4 + 2] + s_part[tid * 4 + 3];
        s_inv[tid] = 1.0f / fmaxf(sqrtf(ssum), 1e-12f);
    }
    __syncthreads();

#pragma unroll
    for (int mi = 0; mi < 2; ++mi)
#pragma unroll
        for (int nj = 0; nj < 2; ++nj)
#pragma unroll
            for (int r = 0; r < 4; ++r) {
                int m = mi * 16 + q * 4 + r;
                int n = nb + nj * 16 + ln;
                out[(rowBase + m) * 128 + n] = zv[mi][nj][r] * s_inv[m];
            }
}

// ---------------------------------------------------------------- launch ----
extern "C" void kernel_launch(void* const* d_in, const int* in_sizes, int n_in,
                              void* d_out, int out_size, void* d_ws, size_t ws_size,
                              hipStream_t stream) {
    const float* x   = (const float*)d_in[0];   // [8192,128]
    const float* adj = (const float*)d_in[1];   // [8192,8192]
    const float* W   = (const float*)d_in[2];   // [128,128]
    const float* b   = (const float*)d_in[3];   // [128]
    float* out = (float*)d_out;

    char* ws = (char*)d_ws;
    unsigned short* adjb = (unsigned short*)ws;                        // 128 MB
    unsigned short* yT   = (unsigned short*)(ws + (134217728L));       // 2 MB
    float*          dv   = (float*)(ws + 134217728L + (2L << 20));     // 32 KB
    unsigned short* Wb   = (unsigned short*)(ws + 134217728L + (2L << 20) + 32768);

    gcn_prep <<<8192, 256, 0, stream>>>(adj, adjb, dv);
    gcn_build<<<128,  256, 0, stream>>>(x, W, dv, yT, Wb);
    gcn_main <<<256,  256, 0, stream>>>(adjb, x, b, yT, dv, Wb, out);
}